// Round 1
// baseline (16841.338 us; speedup 1.0000x reference)
//
#include <hip/hip_runtime.h>

typedef __bf16 bf16_t;
typedef __bf16 bf16x8 __attribute__((ext_vector_type(8)));
typedef float f32x4 __attribute__((ext_vector_type(4)));

constexpr int kB = 64, kT = 256, kE = 128, kH = 1024, kV = 16384;
constexpr int kBT = kB * kT;

// ---------------- zero initial state ----------------
__global__ void zero_state(float* h1f, float* h2f, bf16_t* x2) {
    int i = blockIdx.x * 256 + threadIdx.x;           // grid 512*256 = 131072
    if (i < kB * kH) { h1f[i] = 0.f; h2f[i] = 0.f; }
    if (i < kB * 2 * kH) x2[i] = (bf16_t)0.f;
}

// ---------------- transpose fp32 [R][C] -> bf16 [C][R] ----------------
__global__ void transpose_to_bf16(const float* __restrict__ src, bf16_t* __restrict__ dst,
                                  int R, int C) {
    __shared__ float tile[32][33];
    int c0 = blockIdx.x * 32, r0 = blockIdx.y * 32;
    for (int rr = threadIdx.y; rr < 32; rr += 8)
        tile[rr][threadIdx.x] = src[(size_t)(r0 + rr) * C + c0 + threadIdx.x];
    __syncthreads();
    for (int rr = threadIdx.y; rr < 32; rr += 8)
        dst[(size_t)(c0 + rr) * R + r0 + threadIdx.x] = (bf16_t)tile[threadIdx.x][rr];
}

// ---------------- embedding lookup + x-part of layer1 gates/cand ----------------
// xg1[bt][0:2048] = b_g1 + x @ W_g1[0:128,:]; xc1[bt][0:1024] = b_c1 + x @ W_c1[0:128,:]
__global__ __launch_bounds__(256) void embed_precompute(
    const int* __restrict__ ids, const float* __restrict__ emb,
    const float* __restrict__ Wg1, const float* __restrict__ bg1,
    const float* __restrict__ Wc1, const float* __restrict__ bc1,
    float* __restrict__ xg1, float* __restrict__ xc1) {
    __shared__ float xs[4][kE];
    int bt0 = blockIdx.x * 4;
    int tid = threadIdx.x;
    if (tid < kE) {
        #pragma unroll
        for (int r = 0; r < 4; ++r)
            xs[r][tid] = emb[(size_t)ids[bt0 + r] * kE + tid];
    }
    __syncthreads();
    int jt = blockIdx.y;
    if (jt < 8) {
        int j = jt * 256 + tid;
        float acc[4];
        #pragma unroll
        for (int r = 0; r < 4; ++r) acc[r] = bg1[j];
        for (int k = 0; k < kE; ++k) {
            float wv = Wg1[(size_t)k * 2048 + j];
            #pragma unroll
            for (int r = 0; r < 4; ++r) acc[r] += xs[r][k] * wv;
        }
        #pragma unroll
        for (int r = 0; r < 4; ++r) xg1[(size_t)(bt0 + r) * 2048 + j] = acc[r];
    } else {
        int j = (jt - 8) * 256 + tid;
        float acc[4];
        #pragma unroll
        for (int r = 0; r < 4; ++r) acc[r] = bc1[j];
        for (int k = 0; k < kE; ++k) {
            float wv = Wc1[(size_t)k * 1024 + j];
            #pragma unroll
            for (int r = 0; r < 4; ++r) acc[r] += xs[r][k] * wv;
        }
        #pragma unroll
        for (int r = 0; r < 4; ++r) xc1[(size_t)(bt0 + r) * 1024 + j] = acc[r];
    }
}

// ---------------- generic GRU phase: OUT = epilogue(pre + A[64][K] @ Wt[N][K]^T) -------
// block = 256 threads (4 waves); block covers 64 rows x 32 cols; waves split K 4-way.
// mode 0 (gates):  g=sigmoid(v); j<NH: rh_dst[b][j]=(bf16)(g*hf[b][j]); else u_buf[b][j-NH]=g
// mode 1 (cand):   c=tanh(v); hn=u*h_old+(1-u)*c; hf_dst fp32, d1/d2 bf16 copies
__global__ __launch_bounds__(256) void rnn_phase(
    const bf16_t* __restrict__ A, int a_stride,
    const bf16_t* __restrict__ Wt, int K,
    const float* __restrict__ pre, long pre_stride,
    const float* __restrict__ hf, float* __restrict__ u_buf,
    int NH, int mode,
    bf16_t* __restrict__ rh_dst, int rh_stride,
    float* __restrict__ hf_dst,
    bf16_t* __restrict__ d1, long d1_stride,
    bf16_t* __restrict__ d2, long d2_stride) {
    const int n0 = blockIdx.x * 32;
    const int tid = threadIdx.x;
    const int w = tid >> 6, l = tid & 63;
    const int lr = l & 15, lk = (l >> 4) * 8;
    const int kchunk = K >> 2;
    const int kbeg = w * kchunk;

    f32x4 acc[4][2] = {};
    for (int k0 = kbeg; k0 < kbeg + kchunk; k0 += 32) {
        bf16x8 a[4], bv[2];
        #pragma unroll
        for (int mf = 0; mf < 4; ++mf)
            a[mf] = *reinterpret_cast<const bf16x8*>(A + (size_t)(mf * 16 + lr) * a_stride + k0 + lk);
        #pragma unroll
        for (int nf = 0; nf < 2; ++nf)
            bv[nf] = *reinterpret_cast<const bf16x8*>(Wt + (size_t)(n0 + nf * 16 + lr) * K + k0 + lk);
        #pragma unroll
        for (int mf = 0; mf < 4; ++mf)
            #pragma unroll
            for (int nf = 0; nf < 2; ++nf)
                acc[mf][nf] = __builtin_amdgcn_mfma_f32_16x16x32_bf16(a[mf], bv[nf], acc[mf][nf], 0, 0, 0);
    }

    // cross-wave K-reduction via LDS
    __shared__ float red[4][64][32];
    #pragma unroll
    for (int mf = 0; mf < 4; ++mf)
        #pragma unroll
        for (int nf = 0; nf < 2; ++nf)
            #pragma unroll
            for (int i = 0; i < 4; ++i)
                red[w][mf * 16 + (l >> 4) * 4 + i][nf * 16 + lr] = acc[mf][nf][i];
    __syncthreads();

    const int jl = tid & 31;
    const int jglob = n0 + jl;
    #pragma unroll
    for (int bb = 0; bb < 8; ++bb) {
        int b = (tid >> 5) + bb * 8;
        float v = red[0][b][jl] + red[1][b][jl] + red[2][b][jl] + red[3][b][jl];
        v += pre[(size_t)b * pre_stride + jglob];
        if (mode == 0) {
            float g = 1.f / (1.f + __expf(-v));
            if (jglob < NH) {
                rh_dst[(size_t)b * rh_stride + jglob] = (bf16_t)(g * hf[b * NH + jglob]);
            } else {
                u_buf[b * NH + (jglob - NH)] = g;
            }
        } else {
            float c = tanhf(v);
            float u = u_buf[b * NH + jglob];
            float ho = hf[b * NH + jglob];
            float hn = u * ho + (1.f - u) * c;
            hf_dst[b * NH + jglob] = hn;
            d1[(size_t)b * d1_stride + jglob] = (bf16_t)hn;
            if (d2) d2[(size_t)b * d2_stride + jglob] = (bf16_t)hn;
        }
    }
}

// ---------------- logits GEMM: [16384,1024]bf16 @ [1024,16384] (Bt pre-transposed) ----
__global__ __launch_bounds__(256) void logits_gemm(
    const bf16_t* __restrict__ Amat,   // [kBT][kH]
    const bf16_t* __restrict__ Bt,     // [kV][kH]
    const float* __restrict__ bias,    // [kV]
    float* __restrict__ out) {         // [kBT][kV]
    __shared__ __align__(16) bf16_t As[128 * 64];
    __shared__ __align__(16) bf16_t Bs[128 * 64];
    const int tid = threadIdx.x;
    const int w = tid >> 6, l = tid & 63;
    const int wr = w >> 1, wc = w & 1;
    const int lr = l & 15, lk8 = (l >> 4) * 8;
    const int row0 = blockIdx.y * 128, col0 = blockIdx.x * 128;

    int srow[4], scol[4];
    #pragma unroll
    for (int v = 0; v < 4; ++v) {
        int idx = v * 256 + tid;
        srow[v] = idx >> 3;
        scol[v] = (idx & 7) * 8;
    }

    f32x4 acc[4][4] = {};
    bf16x8 ra[4], rb[4];
    #pragma unroll
    for (int v = 0; v < 4; ++v) {
        ra[v] = *reinterpret_cast<const bf16x8*>(Amat + (size_t)(row0 + srow[v]) * kH + scol[v]);
        rb[v] = *reinterpret_cast<const bf16x8*>(Bt + (size_t)(col0 + srow[v]) * kH + scol[v]);
    }
    for (int kt = 0; kt < 16; ++kt) {
        __syncthreads();
        #pragma unroll
        for (int v = 0; v < 4; ++v) {
            *reinterpret_cast<bf16x8*>(As + srow[v] * 64 + scol[v]) = ra[v];
            *reinterpret_cast<bf16x8*>(Bs + srow[v] * 64 + scol[v]) = rb[v];
        }
        __syncthreads();
        if (kt < 15) {
            int ko = (kt + 1) * 64;
            #pragma unroll
            for (int v = 0; v < 4; ++v) {
                ra[v] = *reinterpret_cast<const bf16x8*>(Amat + (size_t)(row0 + srow[v]) * kH + ko + scol[v]);
                rb[v] = *reinterpret_cast<const bf16x8*>(Bt + (size_t)(col0 + srow[v]) * kH + ko + scol[v]);
            }
        }
        #pragma unroll
        for (int ks = 0; ks < 2; ++ks) {
            bf16x8 af[4], bfv[4];
            #pragma unroll
            for (int mf = 0; mf < 4; ++mf)
                af[mf] = *reinterpret_cast<const bf16x8*>(As + (wr * 64 + mf * 16 + lr) * 64 + ks * 32 + lk8);
            #pragma unroll
            for (int nf = 0; nf < 4; ++nf)
                bfv[nf] = *reinterpret_cast<const bf16x8*>(Bs + (wc * 64 + nf * 16 + lr) * 64 + ks * 32 + lk8);
            #pragma unroll
            for (int mf = 0; mf < 4; ++mf)
                #pragma unroll
                for (int nf = 0; nf < 4; ++nf)
                    acc[mf][nf] = __builtin_amdgcn_mfma_f32_16x16x32_bf16(af[mf], bfv[nf], acc[mf][nf], 0, 0, 0);
        }
    }
    #pragma unroll
    for (int mf = 0; mf < 4; ++mf) {
        int row = row0 + wr * 64 + mf * 16 + (l >> 4) * 4;
        #pragma unroll
        for (int nf = 0; nf < 4; ++nf) {
            int col = col0 + wc * 64 + nf * 16 + lr;
            float bvl = bias[col];
            #pragma unroll
            for (int i = 0; i < 4; ++i)
                out[(size_t)(row + i) * kV + col] = acc[mf][nf][i] + bvl;
        }
    }
}

// ---------------- online log-softmax NLL per row ----------------
__global__ __launch_bounds__(256) void row_nll(const float* __restrict__ logits,
                                               const int* __restrict__ targets,
                                               float* __restrict__ nll) {
    int row = blockIdx.x;
    const float* rowp = logits + (size_t)row * kV;
    int tid = threadIdx.x;
    float m = -1e30f, s = 0.f;
    for (int j = tid; j < kV; j += 256) {
        float v = rowp[j];
        if (v > m) { s = s * __expf(m - v) + 1.f; m = v; }
        else s += __expf(v - m);
    }
    __shared__ float ms[256], ss[256];
    ms[tid] = m; ss[tid] = s;
    __syncthreads();
    for (int off = 128; off; off >>= 1) {
        if (tid < off) {
            float m2 = ms[tid + off], s2 = ss[tid + off];
            float M = fmaxf(ms[tid], m2);
            ss[tid] = ss[tid] * __expf(ms[tid] - M) + s2 * __expf(m2 - M);
            ms[tid] = M;
        }
        __syncthreads();
    }
    if (tid == 0) {
        float lse = ms[0] + __logf(ss[0]);
        nll[row] = lse - rowp[targets[row]];
    }
}

__global__ __launch_bounds__(256) void loss_reduce(const float* __restrict__ nll,
                                                   float* __restrict__ out) {
    __shared__ float sm[256];
    int tid = threadIdx.x;
    float s = 0.f;
    for (int i = tid; i < kBT; i += 256) s += nll[i];
    sm[tid] = s;
    __syncthreads();
    for (int off = 128; off; off >>= 1) {
        if (tid < off) sm[tid] += sm[tid + off];
        __syncthreads();
    }
    if (tid == 0) out[0] = sm[0] / (float)kBT;
}

// ---------------- host ----------------
extern "C" void kernel_launch(void* const* d_in, const int* in_sizes, int n_in,
                              void* d_out, int out_size, void* d_ws, size_t ws_size,
                              hipStream_t stream) {
    const int*   ids = (const int*)d_in[0];
    const int*   tgt = (const int*)d_in[1];
    const float* emb = (const float*)d_in[2];
    const float* Wg1 = (const float*)d_in[3];
    const float* bg1 = (const float*)d_in[4];
    const float* Wc1 = (const float*)d_in[5];
    const float* bc1 = (const float*)d_in[6];
    const float* Wg2 = (const float*)d_in[7];
    const float* bg2 = (const float*)d_in[8];
    const float* Wc2 = (const float*)d_in[9];
    const float* bc2 = (const float*)d_in[10];
    const float* sw  = (const float*)d_in[11];
    const float* sb  = (const float*)d_in[12];
    float* out = (float*)d_out;

    char* ws = (char*)d_ws;
    size_t off = 0;
    auto alloc = [&](size_t bytes) -> void* {
        void* p = ws + off;
        off += (bytes + 255) & ~(size_t)255;
        return p;
    };
    bf16_t* WG1HT = (bf16_t*)alloc((size_t)2048 * 1024 * 2);
    bf16_t* WC1HT = (bf16_t*)alloc((size_t)1024 * 1024 * 2);
    bf16_t* WG2T  = (bf16_t*)alloc((size_t)2048 * 2048 * 2);
    bf16_t* WC2T  = (bf16_t*)alloc((size_t)1024 * 2048 * 2);
    bf16_t* SWT   = (bf16_t*)alloc((size_t)kV * kH * 2);
    float*  XG1   = (float*)alloc((size_t)kBT * 2048 * 4);
    float*  XC1   = (float*)alloc((size_t)kBT * 1024 * 4);
    bf16_t* YS    = (bf16_t*)alloc((size_t)kBT * kH * 2);
    bf16_t* X2    = (bf16_t*)alloc((size_t)kB * 2048 * 2);
    bf16_t* X2C   = (bf16_t*)alloc((size_t)kB * 2048 * 2);
    float*  H1F   = (float*)alloc((size_t)kB * kH * 4);
    float*  H2F   = (float*)alloc((size_t)kB * kH * 4);
    float*  U1    = (float*)alloc((size_t)kB * kH * 4);
    float*  U2    = (float*)alloc((size_t)kB * kH * 4);
    bf16_t* RH1   = (bf16_t*)alloc((size_t)kB * kH * 2);
    float*  NLL   = (float*)alloc((size_t)kBT * 4);

    // weight conversions (bf16, [N][K] layout)
    transpose_to_bf16<<<dim3(64, 32), dim3(32, 8), 0, stream>>>(Wg1 + (size_t)kE * 2048, WG1HT, 1024, 2048);
    transpose_to_bf16<<<dim3(32, 32), dim3(32, 8), 0, stream>>>(Wc1 + (size_t)kE * 1024, WC1HT, 1024, 1024);
    transpose_to_bf16<<<dim3(64, 64), dim3(32, 8), 0, stream>>>(Wg2, WG2T, 2048, 2048);
    transpose_to_bf16<<<dim3(32, 64), dim3(32, 8), 0, stream>>>(Wc2, WC2T, 2048, 1024);
    transpose_to_bf16<<<dim3(512, 32), dim3(32, 8), 0, stream>>>(sw, SWT, 1024, 16384);

    embed_precompute<<<dim3(kBT / 4, 12), 256, 0, stream>>>(ids, emb, Wg1, bg1, Wc1, bc1, XG1, XC1);
    zero_state<<<512, 256, 0, stream>>>(H1F, H2F, X2);

    for (int t = 0; t < kT; ++t) {
        // P1: gates layer1  (A = h1_old in X2[:,0:1024])
        rnn_phase<<<64, 256, 0, stream>>>(X2, 2048, WG1HT, 1024,
                                          XG1 + (size_t)t * 2048, (long)kT * 2048,
                                          H1F, U1, kH, 0,
                                          RH1, 1024, nullptr, nullptr, 0, nullptr, 0);
        // P2: cand layer1 -> h1_new (fp32 H1F; bf16 into X2[:,0:1024] and X2C[:,0:1024])
        rnn_phase<<<32, 256, 0, stream>>>(RH1, 1024, WC1HT, 1024,
                                          XC1 + (size_t)t * 1024, (long)kT * 1024,
                                          H1F, U1, kH, 1,
                                          nullptr, 0, H1F, X2, 2048, X2C, 2048);
        // P3: gates layer2  (A = [h1_new | h2_old] in X2)
        rnn_phase<<<64, 256, 0, stream>>>(X2, 2048, WG2T, 2048,
                                          bg2, 0,
                                          H2F, U2, kH, 0,
                                          X2C + 1024, 2048, nullptr, nullptr, 0, nullptr, 0);
        // P4: cand layer2 -> h2_new (fp32 H2F; bf16 into X2[:,1024:2048] and YS row b*T+t)
        rnn_phase<<<32, 256, 0, stream>>>(X2C, 2048, WC2T, 2048,
                                          bc2, 0,
                                          H2F, U2, kH, 1,
                                          nullptr, 0, H2F, X2 + 1024, 2048,
                                          YS + (size_t)t * 1024, (long)kT * 1024);
    }

    logits_gemm<<<dim3(kV / 128, kBT / 128), 256, 0, stream>>>(YS, SWT, sb, out);
    row_nll<<<kBT, 256, 0, stream>>>(out, tgt, NLL);
    loss_reduce<<<1, 256, 0, stream>>>(NLL, out + (size_t)kBT * kV);
}